// Round 1
// 289.097 us; speedup vs baseline: 1.0509x; 1.0509x over previous
//
#include <hip/hip_runtime.h>

typedef unsigned short u16;
typedef unsigned int   u32;
typedef short  short8   __attribute__((ext_vector_type(8)));
typedef float  floatx4  __attribute__((ext_vector_type(4)));
typedef u16    ushortx2 __attribute__((ext_vector_type(2)));
typedef u16    ushortx4 __attribute__((ext_vector_type(4)));

__device__ __forceinline__ float bf2f(u16 u) {
  union { u32 i; float f; } v; v.i = ((u32)u) << 16; return v.f;
}
__device__ __forceinline__ u16 f2bf(float x) {
  union { float f; u32 i; } v; v.f = x;
  u32 r = v.i + 0x7FFFu + ((v.i >> 16) & 1u);   // round-to-nearest-even
  return (u16)(r >> 16);
}

#if __has_builtin(__builtin_amdgcn_exp2f)
#define EXP2F(x) __builtin_amdgcn_exp2f(x)
#else
#define EXP2F(x) __exp2f(x)
#endif

// async global->LDS, 16B per lane; LDS dest = wave-uniform base + lane*16
#define GLOAD_LDS16(gptr, lptr)                                                   \
  __builtin_amdgcn_global_load_lds(                                               \
      (const __attribute__((address_space(1))) void*)(gptr),                      \
      (__attribute__((address_space(3))) void*)(lptr), 16, 0, 0)

#define WAITV(n) asm volatile("s_waitcnt vmcnt(" #n ")" ::: "memory")
#define WAITL    asm volatile("s_waitcnt lgkmcnt(0)" ::: "memory")
#define BAR      __builtin_amdgcn_s_barrier()

// ---------------------------------------------------------------------------
// fp32 -> bf16 bulk convert, all 5 tensors in one launch (blockIdx.y selects).
// wq/wk/wv land contiguously so the QKV projection is one N=6144 GEMM.
// ---------------------------------------------------------------------------
__global__ __launch_bounds__(256) void cvt_all(
    const floatx4* __restrict__ x,  const floatx4* __restrict__ wq,
    const floatx4* __restrict__ wk, const floatx4* __restrict__ wv,
    const floatx4* __restrict__ wo,
    ushortx4* __restrict__ xb, ushortx4* __restrict__ wqkv,
    ushortx4* __restrict__ wob) {
  int i = blockIdx.x * 256 + threadIdx.x;
  const floatx4* in; ushortx4* out;
  switch (blockIdx.y) {
    case 0:  in = x;  out = xb; break;
    case 1:  in = wq; out = wqkv; break;
    case 2:  in = wk; out = wqkv + (size_t)1048576; break;   // 2048*2048/4
    case 3:  in = wv; out = wqkv + (size_t)2097152; break;
    default: in = wo; out = wob; break;
  }
  floatx4 v = in[i];
  ushortx4 o;
  o.x = f2bf(v.x); o.y = f2bf(v.y); o.z = f2bf(v.z); o.w = f2bf(v.w);
  out[i] = o;
}

// ---------------------------------------------------------------------------
// 256x256 8-wave BT-GEMM, BK=64, phase-split K-loop with counted vmcnt.
// C[m][n] = sum_k A[m][k]*B[n][k], C written bf16.
//
// Wave grid 2(M)x4(N); per-wave output 128x64 but INTERLEAVED across tile
// halves: rows wr*64+{0..63} and 128+wr*64+{0..63}; cols wc*32+{0..31} and
// 128+wc*32+{0..31}. Consequence: phase P1 reads only A-half0+B-half0,
// P2 only B-half1, P3 only A-half1, P4 reuses registers. That alignment is
// what lets a single counted vmcnt(4) per phase (never 0) keep 3-4
// half-tiles of global_load_lds in flight across raw s_barriers (T3+T4).
//
// LDS 128 KiB: As/Bs[2][256][64], seg-XOR swizzle (measured 0 bank
// conflicts in the 128^2 predecessor): element (r,c) at [r][(c>>3 ^ (r&7))<<3
// | (c&7)]; staged by pre-swizzling the *global* source column (rule #21).
//
// Schedule per K-tile t (buf=t&1, staging t+1 into buf^1):
//  P1: ds A(i0-3) + B(j0-1) | stage A-h0(t+1) | vmcnt(4)        | bar | MFMA Q0
//  P2: ds B(j2-3)           | stage B-h0(t+1) | vmcnt(4)        | bar | MFMA Q1
//  P3: ds A(i4-7)           | stage B-h1(t+1) |                 | bar | MFMA Q3
//  P4:                      | stage A-h1(t+1) | lgkm(0) vmcnt(4)| bar | MFMA Q2
// vmcnt(4) at P4 leaves exactly {B-h1,A-h1}(t+1) in flight; P1/P2's vmcnt(4)
// retire them just-in-time for the next tile's P2/P3 reads. lgkmcnt(0) at P4
// guarantees all reads of buf are in registers before t+1's staging
// overwrites it.
// ---------------------------------------------------------------------------
__global__ __launch_bounds__(512, 2) void gemm256_bt(
    const u16* __restrict__ A, const u16* __restrict__ B, u16* __restrict__ C,
    int N, int K, int lda, int ldb, int ldc) {
  // bijective XCD swizzle (gridDim.x % 8 == 0)
  const int cpx = gridDim.x >> 3;
  const int wg = ((int)blockIdx.x & 7) * cpx + ((int)blockIdx.x >> 3);
  const int ntn = N >> 8;
  const int m0 = (wg / ntn) << 8;
  const int n0 = (wg % ntn) << 8;

  __shared__ __align__(16) u16 As[2][256][64];
  __shared__ __align__(16) u16 Bs[2][256][64];

  const int t = threadIdx.x;
  const int lane = t & 63;
  const int wave = t >> 6;
  const int wr = wave >> 2;          // 0..1
  const int wc = wave & 3;           // 0..3
  const int quad = lane >> 4;
  const int mrow = lane & 15;
  const int sw = mrow & 7;

  // staging: per gload, wave writes 1 KiB = 8 rows x 8 segs; global col-seg
  // pre-swizzled so a linear LDS write realizes the seg-XOR layout.
  const int srow = lane >> 3;                    // 0..7
  const int gso  = ((lane & 7) ^ srow) << 3;     // u16 col offset

  const u16* gA = A + (size_t)(m0 + (wave << 3) + srow) * lda + gso;
  const u16* gB = B + (size_t)(n0 + (wave << 3) + srow) * ldb + gso;

  floatx4 acc[8][4] = {};
  short8 afr[4][2], bfr[4][2];

  const int NT = K >> 6;                         // K-tiles (NT >= 2)

#define ST_A(nb, h, kt)                                                        \
  do {                                                                         \
    GLOAD_LDS16(gA + (size_t)((h) * 128) * lda + ((kt) << 6),                  \
                &As[nb][(h) * 128 + (wave << 3)][0]);                          \
    GLOAD_LDS16(gA + (size_t)((h) * 128 + 64) * lda + ((kt) << 6),             \
                &As[nb][(h) * 128 + 64 + (wave << 3)][0]);                     \
  } while (0)
#define ST_B(nb, h, kt)                                                        \
  do {                                                                         \
    GLOAD_LDS16(gB + (size_t)((h) * 128) * ldb + ((kt) << 6),                  \
                &Bs[nb][(h) * 128 + (wave << 3)][0]);                          \
    GLOAD_LDS16(gB + (size_t)((h) * 128 + 64) * ldb + ((kt) << 6),             \
                &Bs[nb][(h) * 128 + 64 + (wave << 3)][0]);                     \
  } while (0)

  // A frags i0..3 from rows base_row + i*16 + mrow of As[bf]
#define LDA4(bf, base_row)                                                     \
  do {                                                                         \
    _Pragma("unroll") for (int i_ = 0; i_ < 4; i_++)                           \
      _Pragma("unroll") for (int kk_ = 0; kk_ < 2; kk_++)                      \
        afr[i_][kk_] = *(const short8*)&As[bf][(base_row) + (i_ << 4) + mrow]  \
                            [(((kk_ << 2) | quad) ^ sw) << 3];                 \
  } while (0)
  // B frags j = jlo, jlo+1 from rows base_row + {0,16} + mrow of Bs[bf]
#define LDB2(bf, jlo, base_row)                                                \
  do {                                                                         \
    _Pragma("unroll") for (int j_ = 0; j_ < 2; j_++)                           \
      _Pragma("unroll") for (int kk_ = 0; kk_ < 2; kk_++)                      \
        bfr[(jlo) + j_][kk_] =                                                 \
            *(const short8*)&Bs[bf][(base_row) + (j_ << 4) + mrow]             \
                [(((kk_ << 2) | quad) ^ sw) << 3];                             \
  } while (0)
  // one quadrant: 4 i x 2 j x 2 kk = 16 MFMA (afr holds the i-set for ilo)
#define MMQ(ilo, jlo)                                                          \
  do {                                                                         \
    __builtin_amdgcn_s_setprio(1);                                             \
    _Pragma("unroll") for (int kk_ = 0; kk_ < 2; kk_++)                        \
      _Pragma("unroll") for (int i_ = 0; i_ < 4; i_++)                         \
        _Pragma("unroll") for (int j_ = 0; j_ < 2; j_++)                       \
          acc[(ilo) + i_][(jlo) + j_] =                                        \
              __builtin_amdgcn_mfma_f32_16x16x32_bf16(                         \
                  afr[i_][kk_], bfr[(jlo) + j_][kk_],                          \
                  acc[(ilo) + i_][(jlo) + j_], 0, 0, 0);                       \
    __builtin_amdgcn_s_setprio(0);                                             \
  } while (0)

  // prologue: stage tile 0 (order: A-h0, B-h0, B-h1, A-h1)
  ST_A(0, 0, 0); ST_B(0, 0, 0); ST_B(0, 1, 0); ST_A(0, 1, 0);
  WAITV(4);                                    // A-h0, B-h0 resident
  BAR;

  for (int kt = 0; kt < NT - 1; kt++) {
    const int bf = kt & 1, nb = bf ^ 1;
    // P1
    LDA4(bf, (wr << 6));                       // A-h0 rows
    LDB2(bf, 0, (wc << 5));                    // B-h0 rows
    ST_A(nb, 0, kt + 1);
    WAITV(4);                                  // B-h1(kt) resident
    BAR;
    MMQ(0, 0);
    // P2
    LDB2(bf, 2, 128 + (wc << 5));              // B-h1 rows
    ST_B(nb, 0, kt + 1);
    WAITV(4);                                  // A-h1(kt) resident
    BAR;
    MMQ(0, 2);
    // P3
    LDA4(bf, 128 + (wr << 6));                 // A-h1 rows
    ST_B(nb, 1, kt + 1);
    BAR;
    MMQ(4, 2);
    // P4
    ST_A(nb, 1, kt + 1);
    WAITL;                                     // all reads of buf bf done
    WAITV(4);                                  // A-h0,B-h0(kt+1) resident
    BAR;
    MMQ(4, 0);
  }
  {                                            // last tile, no staging
    const int bf = (NT - 1) & 1;
    LDA4(bf, (wr << 6));
    LDB2(bf, 0, (wc << 5));
    WAITV(2);                                  // B-h1 resident
    BAR;
    MMQ(0, 0);
    LDB2(bf, 2, 128 + (wc << 5));
    WAITV(0);                                  // A-h1 resident
    BAR;
    MMQ(0, 2);
    LDA4(bf, 128 + (wr << 6));
    WAITL;
    BAR;
    MMQ(4, 2);
    MMQ(4, 0);
  }

  // epilogue. C/D layout: col = lane&15, row = quad*4 + reg
#pragma unroll
  for (int i = 0; i < 8; i++) {
    int row0 = m0 + ((i >= 4) ? 128 : 0) + (wr << 6) + ((i & 3) << 4) + (quad << 2);
#pragma unroll
    for (int j = 0; j < 4; j++) {
      int col = n0 + ((j >= 2) ? 128 : 0) + (wc << 5) + ((j & 1) << 4) + mrow;
#pragma unroll
      for (int r = 0; r < 4; r++)
        C[(size_t)(row0 + r) * ldc + col] = f2bf(acc[i][j][r]);
    }
  }
#undef ST_A
#undef ST_B
#undef LDA4
#undef LDB2
#undef MMQ
}

// ---------------------------------------------------------------------------
// BT-GEMM: C[m][n] = sum_k A[m][k]*B[n][k]. 128x128 tile, BK=64 — kept for
// the output projection (2048x2048: 256^2 tiles would underfill the grid).
// ---------------------------------------------------------------------------
__global__ __launch_bounds__(256) void gemm_bt(
    const u16* __restrict__ A, const u16* __restrict__ B, void* __restrict__ Cv,
    int M, int N, int K, int lda, int ldb, int ldc,
    long batchA, long batchB, long batchC, int outBF16) {
  const int m0 = blockIdx.y << 7;
  const int n0 = blockIdx.x << 7;

  A += (long)blockIdx.z * batchA;
  B += (long)blockIdx.z * batchB;
  const long cbase = (long)blockIdx.z * batchC;

  __shared__ __align__(16) u16 As[128][64];
  __shared__ __align__(16) u16 Bs[128][64];

  const int t = threadIdx.x;
  const int lane = t & 63;
  const int wave = t >> 6;
  const int wm = (wave >> 1) << 6;
  const int wn = (wave & 1) << 6;
  const int quad = lane >> 4;
  const int mrow = lane & 15;
  const int sw8 = mrow & 7;

  floatx4 acc[4][4] = {};

  const int srow = lane >> 3;                       // 0..7 within issue
  const int gseg = (((lane & 7) ^ srow) << 3);      // u16 offset
  const u16* gA = A + (long)(m0 + (wave << 5) + srow) * lda + gseg;
  const u16* gB = B + (long)(n0 + (wave << 5) + srow) * ldb + gseg;

  for (int k0 = 0; k0 < K; k0 += 64) {
    __syncthreads();
#pragma unroll
    for (int ii = 0; ii < 4; ii++) {
      GLOAD_LDS16(gA + k0 + (size_t)(ii << 3) * lda, &As[(wave << 5) + (ii << 3)][0]);
      GLOAD_LDS16(gB + k0 + (size_t)(ii << 3) * ldb, &Bs[(wave << 5) + (ii << 3)][0]);
    }
    __syncthreads();

#pragma unroll
    for (int kh = 0; kh < 2; kh++) {
      const int sidx = ((kh << 2) | quad) ^ sw8;
      short8 af[4], bfr[4];
#pragma unroll
      for (int i = 0; i < 4; i++)
        af[i] = *(const short8*)&As[wm + (i << 4) + mrow][sidx << 3];
#pragma unroll
      for (int j = 0; j < 4; j++)
        bfr[j] = *(const short8*)&Bs[wn + (j << 4) + mrow][sidx << 3];
#pragma unroll
      for (int i = 0; i < 4; i++)
#pragma unroll
        for (int j = 0; j < 4; j++)
          acc[i][j] = __builtin_amdgcn_mfma_f32_16x16x32_bf16(af[i], bfr[j], acc[i][j], 0, 0, 0);
    }
  }

#pragma unroll
  for (int i = 0; i < 4; i++) {
    int row0 = m0 + wm + (i << 4) + (quad << 2);
#pragma unroll
    for (int j = 0; j < 4; j++) {
      int col = n0 + wn + (j << 4) + mrow;
#pragma unroll
      for (int r = 0; r < 4; r++) {
        long idx = cbase + (long)(row0 + r) * ldc + col;
        float val = acc[i][j][r];
        if (outBF16) ((u16*)Cv)[idx] = f2bf(val);
        else         ((float*)Cv)[idx] = val;
      }
    }
  }
}

// ---------------------------------------------------------------------------
// Transpose V (cols 4096..6143 of QKV, ld 6144) -> VT[d][s] (ld 2048).
// ---------------------------------------------------------------------------
__global__ __launch_bounds__(256) void transpose_v(const u16* __restrict__ src,
                                                   u16* __restrict__ dst) {
  __shared__ u16 tile[64][68];
  const int d0 = blockIdx.x << 6;
  const int s0 = blockIdx.y << 6;
  const int tx = (threadIdx.x & 15) << 2;
  const int ty = threadIdx.x >> 4;
#pragma unroll
  for (int rr = 0; rr < 64; rr += 16) {
    ushortx4 v = *(const ushortx4*)(src + (size_t)(s0 + ty + rr) * 6144 + d0 + tx);
    *(ushortx4*)&tile[ty + rr][tx] = v;
  }
  __syncthreads();
#pragma unroll
  for (int rr = 0; rr < 64; rr += 16) {
    int r = ty + rr;
    ushortx4 o;
    o.x = tile[tx + 0][r]; o.y = tile[tx + 1][r];
    o.z = tile[tx + 2][r]; o.w = tile[tx + 3][r];
    *(ushortx4*)(dst + (size_t)(d0 + r) * 2048 + s0 + tx) = o;
  }
}

// ---------------------------------------------------------------------------
// RoPE in-place on QKV (row stride 6144).
// q pre-scaled by log2(e)/sqrt(DH) so flash's softmax is a single exp2.
// ---------------------------------------------------------------------------
__global__ __launch_bounds__(256) void rope_qk(u16* __restrict__ qkv,
                                               const float* __restrict__ cs,
                                               const float* __restrict__ sn) {
  int idx = blockIdx.x * 256 + threadIdx.x;
  int p = idx & 63;
  int h = (idx >> 6) & 15;
  int s = idx >> 10;
  float c  = cs[(s << 6) | p];
  float si = sn[(s << 6) | p];
  float scale = blockIdx.y ? 1.0f : 0.12751743f;   // log2(e)/sqrt(128)
  size_t off = (size_t)s * 6144 + (blockIdx.y ? 2048 : 0) + (h << 7) + (p << 1);
  ushortx2 eo = *(ushortx2*)(qkv + off);
  float e = bf2f(eo.x), o = bf2f(eo.y);
  ushortx2 r;
  r.x = f2bf((e * c - o * si) * scale);
  r.y = f2bf((e * si + o * c) * scale);
  *(ushortx2*)(qkv + off) = r;
}

// ---------------------------------------------------------------------------
// Flash attention v4 (unchanged this round).
// ---------------------------------------------------------------------------
__global__ __launch_bounds__(256, 2) void flash_attn(
    const u16* __restrict__ QKVp, const u16* __restrict__ VTp,
    u16* __restrict__ ATp) {
  const int r0id = (int)blockIdx.x + ((int)blockIdx.y << 5);
  const int h    = r0id & 15;
  const int qsub = 31 - (r0id >> 4);
  const int q0 = qsub << 6;
  const int ktmax = qsub >> 1;

  __shared__ __align__(16) u16 Ks[128][128];    // K tile [s][d]   (32 KB)
  __shared__ __align__(16) u16 Vs[128][128];    // VT tile [d][s]  (32 KB)
  __shared__ __align__(16) u16 Ps[64][128];     // P tile  [q][s]  (16 KB)

  const int t = threadIdx.x;
  const int lane = t & 63;
  const int wave = t >> 6;
  const int quad = lane >> 4;
  const int mrow = lane & 15;
  const int sw   = mrow & 7;
  const int wmS = (wave & 1) << 5;
  const int wnS = (wave >> 1) << 6;
  const int wmV = (wave >> 1) << 6;
  const int wnP = (wave & 1) << 5;

  const int r4  = lane >> 4;
  const int seg = lane & 15;
  const int c0 = ((seg ^ r4) << 3);
  const int c4 = ((seg ^ (r4 + 4)) << 3);

  const u16* qbase = QKVp + (size_t)q0 * 6144 + (h << 7);
  const u16* kbase = QKVp + 2048 + (h << 7);
  const u16* vbase = VTp + (size_t)(h << 7) * 2048;

  short8 aq[2][4];
#pragma unroll
  for (int i = 0; i < 2; i++)
#pragma unroll
    for (int kk = 0; kk < 4; kk++)
      aq[i][kk] = *(const short8*)(qbase + (size_t)(wmS + (i << 4) + mrow) * 6144 +
                                   (kk << 5) + (quad << 3));

  const short8 ones = {0x3F80, 0x3F80, 0x3F80, 0x3F80,
                       0x3F80, 0x3F80, 0x3F80, 0x3F80};   // bf16 1.0 x8

  floatx4 Oa[4][2] = {};
  floatx4 Oa1[2] = {};

  const float C2 = 23.083120654223414f;         // 16*log2(e)

  for (int kt = 0; kt <= ktmax; kt++) {
    __syncthreads();                            // B1: prev PV reads done
    {
      int rr0 = wave << 5;
#pragma unroll
      for (int ii = 0; ii < 8; ii++) {
        int rr = rr0 + (ii << 2);
        GLOAD_LDS16(kbase + (size_t)((kt << 7) + rr + r4) * 6144 + ((ii & 1) ? c4 : c0),
                    &Ks[rr][0]);
        GLOAD_LDS16(vbase + (size_t)(rr + r4) * 2048 + (kt << 7) + ((ii & 1) ? c4 : c0),
                    &Vs[rr][0]);
      }
    }
    __syncthreads();                            // B2: staging complete

    floatx4 sa[2][4] = {};
#pragma unroll
    for (int kk = 0; kk < 4; kk++) {
      short8 bk[4];
#pragma unroll
      for (int j = 0; j < 4; j++)
        bk[j] = *(const short8*)&Ks[wnS + (j << 4) + mrow][(((kk << 2) | quad) ^ sw) << 3];
#pragma unroll
      for (int i = 0; i < 2; i++)
#pragma unroll
        for (int j = 0; j < 4; j++)
          sa[i][j] = __builtin_amdgcn_mfma_f32_16x16x32_bf16(aq[i][kk], bk[j], sa[i][j], 0, 0, 0);
    }
    if (kt == ktmax) {
#pragma unroll
      for (int i = 0; i < 2; i++)
#pragma unroll
        for (int j = 0; j < 4; j++)
#pragma unroll
          for (int r = 0; r < 4; r++) {
            int ql = q0 + wmS + (i << 4) + (quad << 2) + r;
            int sl = (kt << 7) + wnS + (j << 4) + mrow;
            if (sl > ql) sa[i][j][r] = -1e30f;
          }
    }
#pragma unroll
    for (int i = 0; i < 2; i++)
#pragma unroll
      for (int j = 0; j < 4; j++)
#pragma unroll
        for (int r = 0; r < 4; r++) {
          int row = wmS + (i << 4) + (quad << 2) + r;
          int col = wnS + (j << 4) + mrow;
          Ps[row][((((col >> 3) ^ (row & 7)) << 3) | (col & 7))] =
              f2bf(EXP2F(sa[i][j][r] - C2));
        }
    __syncthreads();                            // B3: P visible

#pragma unroll
    for (int kk = 0; kk < 4; kk++) {
      short8 av[4], bp[2];
#pragma unroll
      for (int i = 0; i < 4; i++)
        av[i] = *(const short8*)&Vs[wmV + (i << 4) + mrow][(((kk << 2) | quad) ^ sw) << 3];
#pragma unroll
      for (int j = 0; j < 2; j++)
        bp[j] = *(const short8*)&Ps[wnP + (j << 4) + mrow][(((kk << 2) | quad) ^ sw) << 3];
#pragma unroll
      for (int i = 0; i < 4; i++)
#pragma unroll
        for (int j = 0; j < 2; j++)
          Oa[i][j] = __builtin_amdgcn_mfma_f32_16x16x32_bf16(av[i], bp[j], Oa[i][j], 0, 0, 0);
#pragma unroll
      for (int j = 0; j < 2; j++)
        Oa1[j] = __builtin_amdgcn_mfma_f32_16x16x32_bf16(ones, bp[j], Oa1[j], 0, 0, 0);
    }
  }

  float linv[2];
#pragma unroll
  for (int j = 0; j < 2; j++) linv[j] = 1.f / Oa1[j][0];
#pragma unroll
  for (int i = 0; i < 4; i++) {
    int drow = (h << 7) + wmV + (i << 4) + (quad << 2);
#pragma unroll
    for (int j = 0; j < 2; j++) {
      int col = q0 + wnP + (j << 4) + mrow;
#pragma unroll
      for (int r = 0; r < 4; r++)
        ATp[(size_t)(drow + r) * 2048 + col] = f2bf(Oa[i][j][r] * linv[j]);
    }
  }
}

// out[i] = a[i] + b[i]  (split-K reduce, fp32x4)
__global__ __launch_bounds__(256) void reduce2(const floatx4* __restrict__ a,
                                               const floatx4* __restrict__ b,
                                               floatx4* __restrict__ o) {
  int i = blockIdx.x * 256 + threadIdx.x;
  o[i] = a[i] + b[i];
}

// ---------------------------------------------------------------------------
// Orchestration:
//   QKV = BT256(x, [wq;wk;wv]); VT = transpose(V); rope(Q,K);
//   AT  = flash_attn (512 blocks, heavy-first);  out = BT(AT, wo) (split-K=2).
// ---------------------------------------------------------------------------
extern "C" void kernel_launch(void* const* d_in, const int* in_sizes, int n_in,
                              void* d_out, int out_size, void* d_ws, size_t ws_size,
                              hipStream_t stream) {
  const float* x  = (const float*)d_in[0];
  const float* fc = (const float*)d_in[1];
  const float* fs = (const float*)d_in[2];
  const float* wq = (const float*)d_in[4];
  const float* wk = (const float*)d_in[5];
  const float* wv = (const float*)d_in[6];
  const float* wo = (const float*)d_in[7];
  float* out = (float*)d_out;

  char* ws = (char*)d_ws;
  const size_t MB = 1024 * 1024;
  u16*   XB   = (u16*)(ws + 0 * MB);
  u16*   WQKV = (u16*)(ws + 8 * MB);     // [wq;wk;wv] 6144x2048
  u16*   WOb  = (u16*)(ws + 32 * MB);
  u16*   QKV  = (u16*)(ws + 40 * MB);    // [s][6144]
  u16*   VT   = (u16*)(ws + 64 * MB);    // [d][s]
  u16*   AT   = (u16*)(ws + 72 * MB);    // [(h*128+d)][q]
  float* PART = (float*)(ws + 80 * MB);  // split-K partials (2 x 16 MB)

  int use_split = (ws_size >= 113 * MB);

  dim3 blk(256);
  cvt_all<<<dim3(4096, 5), blk, 0, stream>>>(
      (const floatx4*)x, (const floatx4*)wq, (const floatx4*)wk,
      (const floatx4*)wv, (const floatx4*)wo,
      (ushortx4*)XB, (ushortx4*)WQKV, (ushortx4*)WOb);

  // fused QKV projection: M=2048, N=6144, K=2048 — 256^2 phase-split kernel,
  // 192 blocks (8 m-tiles x 24 n-tiles), 512 threads.
  gemm256_bt<<<dim3(192), dim3(512), 0, stream>>>(XB, WQKV, QKV,
                                                  6144, 2048, 2048, 2048, 6144);

  transpose_v<<<dim3(32, 32), blk, 0, stream>>>(QKV + 4096, VT);
  rope_qk<<<dim3(8192, 2), blk, 0, stream>>>(QKV, fc, fs);

  flash_attn<<<dim3(32, 16), blk, 0, stream>>>(QKV, VT, AT);

  // final projection: out[r][j] = sum_q AT[r][q] * wo[j][q]
  if (use_split) {
    gemm_bt<<<dim3(16, 16, 2), blk, 0, stream>>>(AT, WOb, PART, 2048, 2048, 1024,
                                                 2048, 2048, 2048,
                                                 1024, 1024, (long)2048 * 2048, 0);
    reduce2<<<4096, blk, 0, stream>>>((const floatx4*)PART,
                                      (const floatx4*)(PART + (size_t)2048 * 2048),
                                      (floatx4*)out);
  } else {
    gemm_bt<<<dim3(16, 16, 1), blk, 0, stream>>>(AT, WOb, out, 2048, 2048, 2048,
                                                 2048, 2048, 2048, 0, 0, 0, 0);
  }
}

// Round 2
// 283.743 us; speedup vs baseline: 1.0707x; 1.0189x over previous
//
#include <hip/hip_runtime.h>

typedef unsigned short u16;
typedef unsigned int   u32;
typedef short  short8   __attribute__((ext_vector_type(8)));
typedef float  floatx4  __attribute__((ext_vector_type(4)));
typedef u16    ushortx2 __attribute__((ext_vector_type(2)));
typedef u16    ushortx4 __attribute__((ext_vector_type(4)));

__device__ __forceinline__ float bf2f(u16 u) {
  union { u32 i; float f; } v; v.i = ((u32)u) << 16; return v.f;
}
__device__ __forceinline__ u16 f2bf(float x) {
  union { float f; u32 i; } v; v.f = x;
  u32 r = v.i + 0x7FFFu + ((v.i >> 16) & 1u);   // round-to-nearest-even
  return (u16)(r >> 16);
}

#if __has_builtin(__builtin_amdgcn_exp2f)
#define EXP2F(x) __builtin_amdgcn_exp2f(x)
#else
#define EXP2F(x) __exp2f(x)
#endif

// async global->LDS, 16B per lane; LDS dest = wave-uniform base + lane*16
#define GLOAD_LDS16(gptr, lptr)                                                   \
  __builtin_amdgcn_global_load_lds(                                               \
      (const __attribute__((address_space(1))) void*)(gptr),                      \
      (__attribute__((address_space(3))) void*)(lptr), 16, 0, 0)

#define WAITV(n) asm volatile("s_waitcnt vmcnt(" #n ")" ::: "memory")
#define WAITL    asm volatile("s_waitcnt lgkmcnt(0)" ::: "memory")
#define BAR      __builtin_amdgcn_s_barrier()

// ---------------------------------------------------------------------------
// fp32 -> bf16 bulk convert, all 5 tensors in one launch (blockIdx.y selects).
// wq/wk/wv land contiguously so the QKV projection is one N=6144 GEMM.
// ---------------------------------------------------------------------------
__global__ __launch_bounds__(256) void cvt_all(
    const floatx4* __restrict__ x,  const floatx4* __restrict__ wq,
    const floatx4* __restrict__ wk, const floatx4* __restrict__ wv,
    const floatx4* __restrict__ wo,
    ushortx4* __restrict__ xb, ushortx4* __restrict__ wqkv,
    ushortx4* __restrict__ wob) {
  int i = blockIdx.x * 256 + threadIdx.x;
  const floatx4* in; ushortx4* out;
  switch (blockIdx.y) {
    case 0:  in = x;  out = xb; break;
    case 1:  in = wq; out = wqkv; break;
    case 2:  in = wk; out = wqkv + (size_t)1048576; break;   // 2048*2048/4
    case 3:  in = wv; out = wqkv + (size_t)2097152; break;
    default: in = wo; out = wob; break;
  }
  floatx4 v = in[i];
  ushortx4 o;
  o.x = f2bf(v.x); o.y = f2bf(v.y); o.z = f2bf(v.z); o.w = f2bf(v.w);
  out[i] = o;
}

// ---------------------------------------------------------------------------
// 256x192 8-wave BT-GEMM, BK=64, 5-phase K-loop with counted vmcnt.
// C[m][n] = sum_k A[m][k]*B[n][k], C written bf16.
//
// Retiled from 256x256 (R1): M/256 x N/192 = 8 x 32 = 256 blocks = exactly
// 1 block/CU on MI355X (the 256^2 version's 192 blocks left 25% of CUs idle,
// which capped chip MfmaUtil at 0.75x).
//
// Wave grid 2(M)x4(N); per-wave output 128x48: rows wr*64+{0..63} and
// 128+wr*64+{0..63} (A-halves h0/h1), cols j*64 + wc*16 + {0..15}, j=0..2
// (B-chunks c0/c1/c2 of 64 rows each).
//
// LDS 112 KiB: As[2][256][64], Bs[2][192][64], seg-XOR swizzle: element
// (r,c) at [r][(c>>3 ^ (r&7))<<3 | (c&7)], realized by pre-swizzling the
// *global* source column so the linear gload_lds write lands swizzled.
//
// Per-tile gload FIFO (7): g1,g2=A-h0 @P1 | g3=B-c0 @P2 | g4=B-c1 @P3 |
// g5=B-c2 @P4 | g6,g7=A-h1 @P5.  Residency rule: a chunk's gloads are
// retired by a WAITV one phase BEFORE the phase that ds_reads it, and the
// barrier between publishes it block-wide:
//   P1: ds A-h0,B-c0 | st A-h0' | vmcnt(5)  -> B-c1 resident  | bar | 8 MFMA
//   P2: ds B-c1      | st B-c0' | vmcnt(5)  -> B-c2 resident  | bar | 8 MFMA
//   P3: ds B-c2      | st B-c1' | vmcnt(4)  -> A-h1 resident  | bar | 8 MFMA
//   P4: ds A-h1      | st B-c2' |                             | bar | 8 MFMA
//   P5:              | st A-h1' | lgkm(0); vmcnt(4) -> A-h0',B-c0' | bar | 16 MFMA
// vmcnt never drains to 0 in the main loop; lgkm(0)@P5 drains this buffer's
// ds_reads before the next tile stages over it.
// ---------------------------------------------------------------------------
__global__ __launch_bounds__(512, 2) void gemm256_bt(
    const u16* __restrict__ A, const u16* __restrict__ B, u16* __restrict__ C,
    int N, int K, int lda, int ldb, int ldc) {
  // bijective XCD swizzle (gridDim.x % 8 == 0)
  const int cpx = gridDim.x >> 3;
  const int wg = ((int)blockIdx.x & 7) * cpx + ((int)blockIdx.x >> 3);
  const int ntn = N / 192;
  const int m0 = (wg / ntn) << 8;
  const int n0 = (wg % ntn) * 192;

  __shared__ __align__(16) u16 As[2][256][64];
  __shared__ __align__(16) u16 Bs[2][192][64];

  const int t = threadIdx.x;
  const int lane = t & 63;
  const int wave = t >> 6;
  const int wr = wave >> 2;          // 0..1
  const int wc = wave & 3;           // 0..3
  const int quad = lane >> 4;
  const int mrow = lane & 15;
  const int sw = mrow & 7;

  // staging: per gload, wave writes 1 KiB = 8 rows x 8 segs; global col-seg
  // pre-swizzled so a linear LDS write realizes the seg-XOR layout.
  const int srow = lane >> 3;                    // 0..7
  const int gso  = ((lane & 7) ^ srow) << 3;     // u16 col offset

  const u16* gA = A + (size_t)(m0 + (wave << 3) + srow) * lda + gso;
  const u16* gB = B + (size_t)(n0 + (wave << 3) + srow) * ldb + gso;

  floatx4 acc[8][3] = {};
  short8 afr[4][2], bfr[3][2];

  const int NT = K >> 6;                         // K-tiles (NT >= 2)

#define ST_A(nb, h, kt)                                                        \
  do {                                                                         \
    GLOAD_LDS16(gA + (size_t)((h) * 128) * lda + ((kt) << 6),                  \
                &As[nb][(h) * 128 + (wave << 3)][0]);                          \
    GLOAD_LDS16(gA + (size_t)((h) * 128 + 64) * lda + ((kt) << 6),             \
                &As[nb][(h) * 128 + 64 + (wave << 3)][0]);                     \
  } while (0)
#define ST_B1(nb, c, kt)                                                       \
  do {                                                                         \
    GLOAD_LDS16(gB + (size_t)((c) * 64) * ldb + ((kt) << 6),                   \
                &Bs[nb][(c) * 64 + (wave << 3)][0]);                           \
  } while (0)

  // A frags i0..3 from rows base_row + i*16 + mrow of As[bf]
#define LDA4(bf, base_row)                                                     \
  do {                                                                         \
    _Pragma("unroll") for (int i_ = 0; i_ < 4; i_++)                           \
      _Pragma("unroll") for (int kk_ = 0; kk_ < 2; kk_++)                      \
        afr[i_][kk_] = *(const short8*)&As[bf][(base_row) + (i_ << 4) + mrow]  \
                            [(((kk_ << 2) | quad) ^ sw) << 3];                 \
  } while (0)
  // B frag j from rows j*64 + wc*16 + mrow of Bs[bf]
#define LDB1(bf, j)                                                            \
  do {                                                                         \
    _Pragma("unroll") for (int kk_ = 0; kk_ < 2; kk_++)                        \
      bfr[j][kk_] = *(const short8*)&Bs[bf][(j) * 64 + (wc << 4) + mrow]       \
          [(((kk_ << 2) | quad) ^ sw) << 3];                                   \
  } while (0)
  // one sub-block: 4 i x 1 j x 2 kk = 8 MFMA
#define MMQ8(ilo, j)                                                           \
  do {                                                                         \
    __builtin_amdgcn_s_setprio(1);                                             \
    _Pragma("unroll") for (int kk_ = 0; kk_ < 2; kk_++)                        \
      _Pragma("unroll") for (int i_ = 0; i_ < 4; i_++)                         \
        acc[(ilo) + i_][j] = __builtin_amdgcn_mfma_f32_16x16x32_bf16(          \
            afr[i_][kk_], bfr[j][kk_], acc[(ilo) + i_][j], 0, 0, 0);           \
    __builtin_amdgcn_s_setprio(0);                                             \
  } while (0)

  // prologue: stage tile 0 in FIFO order g1..g7
  ST_A(0, 0, 0); ST_B1(0, 0, 0); ST_B1(0, 1, 0); ST_B1(0, 2, 0); ST_A(0, 1, 0);
  WAITV(4);                                    // A-h0, B-c0 resident
  BAR;

  for (int kt = 0; kt < NT - 1; kt++) {
    const int bf = kt & 1, nb = bf ^ 1;
    // P1
    LDA4(bf, (wr << 6));                       // A-h0 rows
    LDB1(bf, 0);                               // B-c0
    ST_A(nb, 0, kt + 1);
    WAITV(5);                                  // B-c1(kt) resident
    BAR;
    MMQ8(0, 0);
    // P2
    LDB1(bf, 1);                               // B-c1
    ST_B1(nb, 0, kt + 1);
    WAITV(5);                                  // B-c2(kt) resident
    BAR;
    MMQ8(0, 1);
    // P3
    LDB1(bf, 2);                               // B-c2
    ST_B1(nb, 1, kt + 1);
    WAITV(4);                                  // A-h1(kt) resident
    BAR;
    MMQ8(0, 2);
    // P4
    LDA4(bf, 128 + (wr << 6));                 // A-h1 rows
    ST_B1(nb, 2, kt + 1);
    BAR;
    MMQ8(4, 0);
    // P5
    ST_A(nb, 1, kt + 1);
    WAITL;                                     // all reads of buf bf done
    WAITV(4);                                  // A-h0,B-c0(kt+1) resident
    BAR;
    MMQ8(4, 1);
    MMQ8(4, 2);
  }
  {                                            // last tile, no staging
    const int bf = (NT - 1) & 1;
    LDA4(bf, (wr << 6));
    LDB1(bf, 0);
    WAITV(3);                                  // B-c1 resident
    BAR;
    MMQ8(0, 0);
    LDB1(bf, 1);
    WAITV(2);                                  // B-c2 resident
    BAR;
    MMQ8(0, 1);
    LDB1(bf, 2);
    WAITV(0);                                  // A-h1 resident
    BAR;
    MMQ8(0, 2);
    LDA4(bf, 128 + (wr << 6));
    BAR;
    MMQ8(4, 0);
    MMQ8(4, 1);
    MMQ8(4, 2);
  }

  // epilogue. C/D layout: col = lane&15, row = quad*4 + reg
#pragma unroll
  for (int i = 0; i < 8; i++) {
    int row0 = m0 + ((i >= 4) ? 128 : 0) + (wr << 6) + ((i & 3) << 4) + (quad << 2);
#pragma unroll
    for (int j = 0; j < 3; j++) {
      int col = n0 + j * 64 + (wc << 4) + mrow;
#pragma unroll
      for (int r = 0; r < 4; r++)
        C[(size_t)(row0 + r) * ldc + col] = f2bf(acc[i][j][r]);
    }
  }
#undef ST_A
#undef ST_B1
#undef LDA4
#undef LDB1
#undef MMQ8
}

// ---------------------------------------------------------------------------
// BT-GEMM: C[m][n] = sum_k A[m][k]*B[n][k]. 128x128 tile, BK=64 — kept for
// the output projection (2048x2048 split-K keeps grid fill there).
// ---------------------------------------------------------------------------
__global__ __launch_bounds__(256) void gemm_bt(
    const u16* __restrict__ A, const u16* __restrict__ B, void* __restrict__ Cv,
    int M, int N, int K, int lda, int ldb, int ldc,
    long batchA, long batchB, long batchC, int outBF16) {
  const int m0 = blockIdx.y << 7;
  const int n0 = blockIdx.x << 7;

  A += (long)blockIdx.z * batchA;
  B += (long)blockIdx.z * batchB;
  const long cbase = (long)blockIdx.z * batchC;

  __shared__ __align__(16) u16 As[128][64];
  __shared__ __align__(16) u16 Bs[128][64];

  const int t = threadIdx.x;
  const int lane = t & 63;
  const int wave = t >> 6;
  const int wm = (wave >> 1) << 6;
  const int wn = (wave & 1) << 6;
  const int quad = lane >> 4;
  const int mrow = lane & 15;
  const int sw8 = mrow & 7;

  floatx4 acc[4][4] = {};

  const int srow = lane >> 3;                       // 0..7 within issue
  const int gseg = (((lane & 7) ^ srow) << 3);      // u16 offset
  const u16* gA = A + (long)(m0 + (wave << 5) + srow) * lda + gseg;
  const u16* gB = B + (long)(n0 + (wave << 5) + srow) * ldb + gseg;

  for (int k0 = 0; k0 < K; k0 += 64) {
    __syncthreads();
#pragma unroll
    for (int ii = 0; ii < 4; ii++) {
      GLOAD_LDS16(gA + k0 + (size_t)(ii << 3) * lda, &As[(wave << 5) + (ii << 3)][0]);
      GLOAD_LDS16(gB + k0 + (size_t)(ii << 3) * ldb, &Bs[(wave << 5) + (ii << 3)][0]);
    }
    __syncthreads();

#pragma unroll
    for (int kh = 0; kh < 2; kh++) {
      const int sidx = ((kh << 2) | quad) ^ sw8;
      short8 af[4], bfr[4];
#pragma unroll
      for (int i = 0; i < 4; i++)
        af[i] = *(const short8*)&As[wm + (i << 4) + mrow][sidx << 3];
#pragma unroll
      for (int j = 0; j < 4; j++)
        bfr[j] = *(const short8*)&Bs[wn + (j << 4) + mrow][sidx << 3];
#pragma unroll
      for (int i = 0; i < 4; i++)
#pragma unroll
        for (int j = 0; j < 4; j++)
          acc[i][j] = __builtin_amdgcn_mfma_f32_16x16x32_bf16(af[i], bfr[j], acc[i][j], 0, 0, 0);
    }
  }

#pragma unroll
  for (int i = 0; i < 4; i++) {
    int row0 = m0 + wm + (i << 4) + (quad << 2);
#pragma unroll
    for (int j = 0; j < 4; j++) {
      int col = n0 + wn + (j << 4) + mrow;
#pragma unroll
      for (int r = 0; r < 4; r++) {
        long idx = cbase + (long)(row0 + r) * ldc + col;
        float val = acc[i][j][r];
        if (outBF16) ((u16*)Cv)[idx] = f2bf(val);
        else         ((float*)Cv)[idx] = val;
      }
    }
  }
}

// ---------------------------------------------------------------------------
// Transpose V (cols 4096..6143 of QKV, ld 6144) -> VT[d][s] (ld 2048).
// ---------------------------------------------------------------------------
__global__ __launch_bounds__(256) void transpose_v(const u16* __restrict__ src,
                                                   u16* __restrict__ dst) {
  __shared__ u16 tile[64][68];
  const int d0 = blockIdx.x << 6;
  const int s0 = blockIdx.y << 6;
  const int tx = (threadIdx.x & 15) << 2;
  const int ty = threadIdx.x >> 4;
#pragma unroll
  for (int rr = 0; rr < 64; rr += 16) {
    ushortx4 v = *(const ushortx4*)(src + (size_t)(s0 + ty + rr) * 6144 + d0 + tx);
    *(ushortx4*)&tile[ty + rr][tx] = v;
  }
  __syncthreads();
#pragma unroll
  for (int rr = 0; rr < 64; rr += 16) {
    int r = ty + rr;
    ushortx4 o;
    o.x = tile[tx + 0][r]; o.y = tile[tx + 1][r];
    o.z = tile[tx + 2][r]; o.w = tile[tx + 3][r];
    *(ushortx4*)(dst + (size_t)(d0 + r) * 2048 + s0 + tx) = o;
  }
}

// ---------------------------------------------------------------------------
// RoPE in-place on QKV (row stride 6144).
// q pre-scaled by log2(e)/sqrt(DH) so flash's softmax is a single exp2.
// ---------------------------------------------------------------------------
__global__ __launch_bounds__(256) void rope_qk(u16* __restrict__ qkv,
                                               const float* __restrict__ cs,
                                               const float* __restrict__ sn) {
  int idx = blockIdx.x * 256 + threadIdx.x;
  int p = idx & 63;
  int h = (idx >> 6) & 15;
  int s = idx >> 10;
  float c  = cs[(s << 6) | p];
  float si = sn[(s << 6) | p];
  float scale = blockIdx.y ? 1.0f : 0.12751743f;   // log2(e)/sqrt(128)
  size_t off = (size_t)s * 6144 + (blockIdx.y ? 2048 : 0) + (h << 7) + (p << 1);
  ushortx2 eo = *(ushortx2*)(qkv + off);
  float e = bf2f(eo.x), o = bf2f(eo.y);
  ushortx2 r;
  r.x = f2bf((e * c - o * si) * scale);
  r.y = f2bf((e * si + o * c) * scale);
  *(ushortx2*)(qkv + off) = r;
}

// ---------------------------------------------------------------------------
// Flash attention v4 (unchanged this round).
// ---------------------------------------------------------------------------
__global__ __launch_bounds__(256, 2) void flash_attn(
    const u16* __restrict__ QKVp, const u16* __restrict__ VTp,
    u16* __restrict__ ATp) {
  const int r0id = (int)blockIdx.x + ((int)blockIdx.y << 5);
  const int h    = r0id & 15;
  const int qsub = 31 - (r0id >> 4);
  const int q0 = qsub << 6;
  const int ktmax = qsub >> 1;

  __shared__ __align__(16) u16 Ks[128][128];    // K tile [s][d]   (32 KB)
  __shared__ __align__(16) u16 Vs[128][128];    // VT tile [d][s]  (32 KB)
  __shared__ __align__(16) u16 Ps[64][128];     // P tile  [q][s]  (16 KB)

  const int t = threadIdx.x;
  const int lane = t & 63;
  const int wave = t >> 6;
  const int quad = lane >> 4;
  const int mrow = lane & 15;
  const int sw   = mrow & 7;
  const int wmS = (wave & 1) << 5;
  const int wnS = (wave >> 1) << 6;
  const int wmV = (wave >> 1) << 6;
  const int wnP = (wave & 1) << 5;

  const int r4  = lane >> 4;
  const int seg = lane & 15;
  const int c0 = ((seg ^ r4) << 3);
  const int c4 = ((seg ^ (r4 + 4)) << 3);

  const u16* qbase = QKVp + (size_t)q0 * 6144 + (h << 7);
  const u16* kbase = QKVp + 2048 + (h << 7);
  const u16* vbase = VTp + (size_t)(h << 7) * 2048;

  short8 aq[2][4];
#pragma unroll
  for (int i = 0; i < 2; i++)
#pragma unroll
    for (int kk = 0; kk < 4; kk++)
      aq[i][kk] = *(const short8*)(qbase + (size_t)(wmS + (i << 4) + mrow) * 6144 +
                                   (kk << 5) + (quad << 3));

  const short8 ones = {0x3F80, 0x3F80, 0x3F80, 0x3F80,
                       0x3F80, 0x3F80, 0x3F80, 0x3F80};   // bf16 1.0 x8

  floatx4 Oa[4][2] = {};
  floatx4 Oa1[2] = {};

  const float C2 = 23.083120654223414f;         // 16*log2(e)

  for (int kt = 0; kt <= ktmax; kt++) {
    __syncthreads();                            // B1: prev PV reads done
    {
      int rr0 = wave << 5;
#pragma unroll
      for (int ii = 0; ii < 8; ii++) {
        int rr = rr0 + (ii << 2);
        GLOAD_LDS16(kbase + (size_t)((kt << 7) + rr + r4) * 6144 + ((ii & 1) ? c4 : c0),
                    &Ks[rr][0]);
        GLOAD_LDS16(vbase + (size_t)(rr + r4) * 2048 + (kt << 7) + ((ii & 1) ? c4 : c0),
                    &Vs[rr][0]);
      }
    }
    __syncthreads();                            // B2: staging complete

    floatx4 sa[2][4] = {};
#pragma unroll
    for (int kk = 0; kk < 4; kk++) {
      short8 bk[4];
#pragma unroll
      for (int j = 0; j < 4; j++)
        bk[j] = *(const short8*)&Ks[wnS + (j << 4) + mrow][(((kk << 2) | quad) ^ sw) << 3];
#pragma unroll
      for (int i = 0; i < 2; i++)
#pragma unroll
        for (int j = 0; j < 4; j++)
          sa[i][j] = __builtin_amdgcn_mfma_f32_16x16x32_bf16(aq[i][kk], bk[j], sa[i][j], 0, 0, 0);
    }
    if (kt == ktmax) {
#pragma unroll
      for (int i = 0; i < 2; i++)
#pragma unroll
        for (int j = 0; j < 4; j++)
#pragma unroll
          for (int r = 0; r < 4; r++) {
            int ql = q0 + wmS + (i << 4) + (quad << 2) + r;
            int sl = (kt << 7) + wnS + (j << 4) + mrow;
            if (sl > ql) sa[i][j][r] = -1e30f;
          }
    }
#pragma unroll
    for (int i = 0; i < 2; i++)
#pragma unroll
      for (int j = 0; j < 4; j++)
#pragma unroll
        for (int r = 0; r < 4; r++) {
          int row = wmS + (i << 4) + (quad << 2) + r;
          int col = wnS + (j << 4) + mrow;
          Ps[row][((((col >> 3) ^ (row & 7)) << 3) | (col & 7))] =
              f2bf(EXP2F(sa[i][j][r] - C2));
        }
    __syncthreads();                            // B3: P visible

#pragma unroll
    for (int kk = 0; kk < 4; kk++) {
      short8 av[4], bp[2];
#pragma unroll
      for (int i = 0; i < 4; i++)
        av[i] = *(const short8*)&Vs[wmV + (i << 4) + mrow][(((kk << 2) | quad) ^ sw) << 3];
#pragma unroll
      for (int j = 0; j < 2; j++)
        bp[j] = *(const short8*)&Ps[wnP + (j << 4) + mrow][(((kk << 2) | quad) ^ sw) << 3];
#pragma unroll
      for (int i = 0; i < 4; i++)
#pragma unroll
        for (int j = 0; j < 2; j++)
          Oa[i][j] = __builtin_amdgcn_mfma_f32_16x16x32_bf16(av[i], bp[j], Oa[i][j], 0, 0, 0);
#pragma unroll
      for (int j = 0; j < 2; j++)
        Oa1[j] = __builtin_amdgcn_mfma_f32_16x16x32_bf16(ones, bp[j], Oa1[j], 0, 0, 0);
    }
  }

  float linv[2];
#pragma unroll
  for (int j = 0; j < 2; j++) linv[j] = 1.f / Oa1[j][0];
#pragma unroll
  for (int i = 0; i < 4; i++) {
    int drow = (h << 7) + wmV + (i << 4) + (quad << 2);
#pragma unroll
    for (int j = 0; j < 2; j++) {
      int col = q0 + wnP + (j << 4) + mrow;
#pragma unroll
      for (int r = 0; r < 4; r++)
        ATp[(size_t)(drow + r) * 2048 + col] = f2bf(Oa[i][j][r] * linv[j]);
    }
  }
}

// out[i] = a[i] + b[i]  (split-K reduce, fp32x4)
__global__ __launch_bounds__(256) void reduce2(const floatx4* __restrict__ a,
                                               const floatx4* __restrict__ b,
                                               floatx4* __restrict__ o) {
  int i = blockIdx.x * 256 + threadIdx.x;
  o[i] = a[i] + b[i];
}

// ---------------------------------------------------------------------------
// Orchestration:
//   QKV = BT256x192(x, [wq;wk;wv]); VT = transpose(V); rope(Q,K);
//   AT  = flash_attn (512 blocks, heavy-first);  out = BT(AT, wo) (split-K=2).
// ---------------------------------------------------------------------------
extern "C" void kernel_launch(void* const* d_in, const int* in_sizes, int n_in,
                              void* d_out, int out_size, void* d_ws, size_t ws_size,
                              hipStream_t stream) {
  const float* x  = (const float*)d_in[0];
  const float* fc = (const float*)d_in[1];
  const float* fs = (const float*)d_in[2];
  const float* wq = (const float*)d_in[4];
  const float* wk = (const float*)d_in[5];
  const float* wv = (const float*)d_in[6];
  const float* wo = (const float*)d_in[7];
  float* out = (float*)d_out;

  char* ws = (char*)d_ws;
  const size_t MB = 1024 * 1024;
  u16*   XB   = (u16*)(ws + 0 * MB);
  u16*   WQKV = (u16*)(ws + 8 * MB);     // [wq;wk;wv] 6144x2048
  u16*   WOb  = (u16*)(ws + 32 * MB);
  u16*   QKV  = (u16*)(ws + 40 * MB);    // [s][6144]
  u16*   VT   = (u16*)(ws + 64 * MB);    // [d][s]
  u16*   AT   = (u16*)(ws + 72 * MB);    // [(h*128+d)][q]
  float* PART = (float*)(ws + 80 * MB);  // split-K partials (2 x 16 MB)

  int use_split = (ws_size >= 113 * MB);

  dim3 blk(256);
  cvt_all<<<dim3(4096, 5), blk, 0, stream>>>(
      (const floatx4*)x, (const floatx4*)wq, (const floatx4*)wk,
      (const floatx4*)wv, (const floatx4*)wo,
      (ushortx4*)XB, (ushortx4*)WQKV, (ushortx4*)WOb);

  // fused QKV projection: M=2048, N=6144, K=2048 — 256x192 tiles,
  // 8 x 32 = 256 blocks (exactly 1/CU), 512 threads.
  gemm256_bt<<<dim3(256), dim3(512), 0, stream>>>(XB, WQKV, QKV,
                                                  6144, 2048, 2048, 2048, 6144);

  transpose_v<<<dim3(32, 32), blk, 0, stream>>>(QKV + 4096, VT);
  rope_qk<<<dim3(8192, 2), blk, 0, stream>>>(QKV, fc, fs);

  flash_attn<<<dim3(32, 16), blk, 0, stream>>>(QKV, VT, AT);

  // final projection: out[r][j] = sum_q AT[r][q] * wo[j][q]
  if (use_split) {
    gemm_bt<<<dim3(16, 16, 2), blk, 0, stream>>>(AT, WOb, PART, 2048, 2048, 1024,
                                                 2048, 2048, 2048,
                                                 1024, 1024, (long)2048 * 2048, 0);
    reduce2<<<4096, blk, 0, stream>>>((const floatx4*)PART,
                                      (const floatx4*)(PART + (size_t)2048 * 2048),
                                      (floatx4*)out);
  } else {
    gemm_bt<<<dim3(16, 16, 1), blk, 0, stream>>>(AT, WOb, out, 2048, 2048, 2048,
                                                 2048, 2048, 2048, 0, 0, 0, 0);
  }
}

// Round 3
// 274.601 us; speedup vs baseline: 1.1064x; 1.0333x over previous
//
#include <hip/hip_runtime.h>

typedef unsigned short u16;
typedef unsigned int   u32;
typedef short  short8   __attribute__((ext_vector_type(8)));
typedef float  floatx4  __attribute__((ext_vector_type(4)));
typedef u16    ushortx2 __attribute__((ext_vector_type(2)));
typedef u16    ushortx4 __attribute__((ext_vector_type(4)));

__device__ __forceinline__ float bf2f(u16 u) {
  union { u32 i; float f; } v; v.i = ((u32)u) << 16; return v.f;
}
__device__ __forceinline__ u16 f2bf(float x) {
  union { float f; u32 i; } v; v.f = x;
  u32 r = v.i + 0x7FFFu + ((v.i >> 16) & 1u);   // round-to-nearest-even
  return (u16)(r >> 16);
}

#if __has_builtin(__builtin_amdgcn_exp2f)
#define EXP2F(x) __builtin_amdgcn_exp2f(x)
#else
#define EXP2F(x) __exp2f(x)
#endif

// async global->LDS, 16B per lane; LDS dest = wave-uniform base + lane*16
#define GLOAD_LDS16(gptr, lptr)                                                   \
  __builtin_amdgcn_global_load_lds(                                               \
      (const __attribute__((address_space(1))) void*)(gptr),                      \
      (__attribute__((address_space(3))) void*)(lptr), 16, 0, 0)

#define WAITV(n) asm volatile("s_waitcnt vmcnt(" #n ")" ::: "memory")
#define WAITL    asm volatile("s_waitcnt lgkmcnt(0)" ::: "memory")
#define BAR      __builtin_amdgcn_s_barrier()

// ---------------------------------------------------------------------------
// fp32 -> bf16 bulk convert, all 5 tensors in one launch (blockIdx.y selects).
// wq/wk/wv land contiguously so the QKV projection is one N=6144 GEMM.
// ---------------------------------------------------------------------------
__global__ __launch_bounds__(256) void cvt_all(
    const floatx4* __restrict__ x,  const floatx4* __restrict__ wq,
    const floatx4* __restrict__ wk, const floatx4* __restrict__ wv,
    const floatx4* __restrict__ wo,
    ushortx4* __restrict__ xb, ushortx4* __restrict__ wqkv,
    ushortx4* __restrict__ wob) {
  int i = blockIdx.x * 256 + threadIdx.x;
  const floatx4* in; ushortx4* out;
  switch (blockIdx.y) {
    case 0:  in = x;  out = xb; break;
    case 1:  in = wq; out = wqkv; break;
    case 2:  in = wk; out = wqkv + (size_t)1048576; break;   // 2048*2048/4
    case 3:  in = wv; out = wqkv + (size_t)2097152; break;
    default: in = wo; out = wob; break;
  }
  floatx4 v = in[i];
  ushortx4 o;
  o.x = f2bf(v.x); o.y = f2bf(v.y); o.z = f2bf(v.z); o.w = f2bf(v.w);
  out[i] = o;
}

// ---------------------------------------------------------------------------
// 256x192 8-wave BT-GEMM, BK=64, 3-phase K-loop (16 MFMA/phase), counted
// vmcnt.  C[m][n] = sum_k A[m][k]*B[n][k], C written bf16.
//
// Geometry (R2): 8 x 32 = 256 blocks = 1/CU. R2's 5-phase/8-MFMA schedule
// measured 34% per-block MFMA efficiency vs R1's 42% (16-MFMA phases) —
// per-phase fixed cost (barrier+wait) amortized over too little work. This
// round: same geometry, 3 phases x 16 MFMA (3 barriers per 48 MFMA).
//
// Per-wave output 128x48: A-halves h0/h1 = rows {wr*64..}/{128+wr*64..},
// B-chunks c0/c1/c2 of 64 rows; acc[8][3].
//
// LDS 112 KiB: As[2][256][64], Bs[2][192][64], seg-XOR swizzle: element
// (r,c) at [r][(c>>3 ^ (r&7))<<3 | (c&7)], realized by pre-swizzling the
// *global* source column so the linear gload_lds write lands swizzled.
//
// Per-tile gload FIFO (7): g1,g2=A-h0 | g3=B0 | g4=B1 | g5=B2 | g6,g7=A-h1.
// Reads: P1 consumes g1..g4, P2 consumes g5..g7, P3 none (register-only).
// Issue spread (tile kt+1, during kt): P1: g1..g3 | P2: g4,g5 | P3: g6,g7.
// Waits (each covers the NEXT phase's ds_reads; never vmcnt(0) in loop):
//   P1: ds A-h0,B0,B1 | st g1-3' | vmcnt(3) -> kt fully resident | bar | 16 MFMA
//   P2: ds B2 (+A-h1 mid-MFMA) | st g4,5' |                      | bar | 16 MFMA
//   P3:                        | st g6,7' | vmcnt(3) -> g1-4' in | bar | 16 MFMA
// Cross-wave overwrite safety: P3 has no ds_reads, and every ds_read is
// consumed by an MFMA in its own or the following phase before the barrier
// that precedes any staging write to those rows (traced per-row above).
// ---------------------------------------------------------------------------
__global__ __launch_bounds__(512, 2) void gemm256_bt(
    const u16* __restrict__ A, const u16* __restrict__ B, u16* __restrict__ C,
    int N, int K, int lda, int ldb, int ldc) {
  // bijective XCD swizzle (gridDim.x % 8 == 0)
  const int cpx = gridDim.x >> 3;
  const int wg = ((int)blockIdx.x & 7) * cpx + ((int)blockIdx.x >> 3);
  const int ntn = N / 192;
  const int m0 = (wg / ntn) << 8;
  const int n0 = (wg % ntn) * 192;

  __shared__ __align__(16) u16 As[2][256][64];
  __shared__ __align__(16) u16 Bs[2][192][64];

  const int t = threadIdx.x;
  const int lane = t & 63;
  const int wave = t >> 6;
  const int wr = wave >> 2;          // 0..1
  const int wc = wave & 3;           // 0..3
  const int quad = lane >> 4;
  const int mrow = lane & 15;
  const int sw = mrow & 7;

  // staging: per gload, wave writes 1 KiB = 8 rows x 8 segs; global col-seg
  // pre-swizzled so a linear LDS write realizes the seg-XOR layout.
  const int srow = lane >> 3;                    // 0..7
  const int gso  = ((lane & 7) ^ srow) << 3;     // u16 col offset

  const u16* gA = A + (size_t)(m0 + (wave << 3) + srow) * lda + gso;
  const u16* gB = B + (size_t)(n0 + (wave << 3) + srow) * ldb + gso;

  floatx4 acc[8][3] = {};
  short8 afr[4][2], bfr[3][2];

  const int NT = K >> 6;                         // K-tiles (NT >= 2)

#define ST_A(nb, h, kt)                                                        \
  do {                                                                         \
    GLOAD_LDS16(gA + (size_t)((h) * 128) * lda + ((kt) << 6),                  \
                &As[nb][(h) * 128 + (wave << 3)][0]);                          \
    GLOAD_LDS16(gA + (size_t)((h) * 128 + 64) * lda + ((kt) << 6),             \
                &As[nb][(h) * 128 + 64 + (wave << 3)][0]);                     \
  } while (0)
#define ST_B1(nb, c, kt)                                                       \
  do {                                                                         \
    GLOAD_LDS16(gB + (size_t)((c) * 64) * ldb + ((kt) << 6),                   \
                &Bs[nb][(c) * 64 + (wave << 3)][0]);                           \
  } while (0)

  // A frags i0..3 from rows base_row + i*16 + mrow of As[bf]
#define LDA4(bf, base_row)                                                     \
  do {                                                                         \
    _Pragma("unroll") for (int i_ = 0; i_ < 4; i_++)                           \
      _Pragma("unroll") for (int kk_ = 0; kk_ < 2; kk_++)                      \
        afr[i_][kk_] = *(const short8*)&As[bf][(base_row) + (i_ << 4) + mrow]  \
                            [(((kk_ << 2) | quad) ^ sw) << 3];                 \
  } while (0)
  // B frag j from rows j*64 + wc*16 + mrow of Bs[bf]
#define LDB1(bf, j)                                                            \
  do {                                                                         \
    _Pragma("unroll") for (int kk_ = 0; kk_ < 2; kk_++)                        \
      bfr[j][kk_] = *(const short8*)&Bs[bf][(j) * 64 + (wc << 4) + mrow]       \
          [(((kk_ << 2) | quad) ^ sw) << 3];                                   \
  } while (0)
  // one sub-block: 4 i x 1 j x 2 kk = 8 MFMA (afr holds the i-set for ilo)
#define MMQ8(ilo, j)                                                           \
  do {                                                                         \
    __builtin_amdgcn_s_setprio(1);                                             \
    _Pragma("unroll") for (int kk_ = 0; kk_ < 2; kk_++)                        \
      _Pragma("unroll") for (int i_ = 0; i_ < 4; i_++)                         \
        acc[(ilo) + i_][j] = __builtin_amdgcn_mfma_f32_16x16x32_bf16(          \
            afr[i_][kk_], bfr[j][kk_], acc[(ilo) + i_][j], 0, 0, 0);           \
    __builtin_amdgcn_s_setprio(0);                                             \
  } while (0)

  // prologue: stage tile 0 in FIFO order g1..g7
  ST_A(0, 0, 0); ST_B1(0, 0, 0); ST_B1(0, 1, 0); ST_B1(0, 2, 0); ST_A(0, 1, 0);
  WAITV(3);                                    // g1..g4 resident for P1
  BAR;

  for (int kt = 0; kt < NT - 1; kt++) {
    const int bf = kt & 1, nb = bf ^ 1;
    // ---- P1: reads g1..g4(kt); issues g1..g3(kt+1) ----
    LDA4(bf, (wr << 6));                       // A-h0 rows
    LDB1(bf, 0);                               // B-c0
    LDB1(bf, 1);                               // B-c1
    ST_A(nb, 0, kt + 1);                       // g1',g2'
    ST_B1(nb, 0, kt + 1);                      // g3'
    WAITV(3);                                  // kt g5..g7 resident (P2 reads)
    BAR;
    MMQ8(0, 0);
    MMQ8(0, 1);
    // ---- P2: reads g5..g7(kt); issues g4,g5(kt+1) ----
    LDB1(bf, 2);                               // B-c2
    ST_B1(nb, 1, kt + 1);                      // g4'
    ST_B1(nb, 2, kt + 1);                      // g5'
    BAR;                                       // no wait: P3 reads nothing
    MMQ8(0, 2);
    LDA4(bf, 128 + (wr << 6));                 // A-h1 (g6,g7 resident via P1 wait)
    MMQ8(4, 0);
    // ---- P3: register-only; issues g6,g7(kt+1) ----
    ST_A(nb, 1, kt + 1);                       // g6',g7'
    WAITV(3);                                  // kt+1 g1..g4 resident (next P1)
    BAR;
    MMQ8(4, 1);
    MMQ8(4, 2);
  }
  {                                            // last tile, no staging
    const int bf = (NT - 1) & 1;
    LDA4(bf, (wr << 6));
    LDB1(bf, 0);
    LDB1(bf, 1);
    WAITV(0);                                  // g5..g7 resident
    BAR;
    MMQ8(0, 0);
    MMQ8(0, 1);
    LDB1(bf, 2);
    BAR;
    MMQ8(0, 2);
    LDA4(bf, 128 + (wr << 6));
    MMQ8(4, 0);
    BAR;
    MMQ8(4, 1);
    MMQ8(4, 2);
  }

  // epilogue. C/D layout: col = lane&15, row = quad*4 + reg
#pragma unroll
  for (int i = 0; i < 8; i++) {
    int row0 = m0 + ((i >= 4) ? 128 : 0) + (wr << 6) + ((i & 3) << 4) + (quad << 2);
#pragma unroll
    for (int j = 0; j < 3; j++) {
      int col = n0 + j * 64 + (wc << 4) + mrow;
#pragma unroll
      for (int r = 0; r < 4; r++)
        C[(size_t)(row0 + r) * ldc + col] = f2bf(acc[i][j][r]);
    }
  }
#undef ST_A
#undef ST_B1
#undef LDA4
#undef LDB1
#undef MMQ8
}

// ---------------------------------------------------------------------------
// BT-GEMM: C[m][n] = sum_k A[m][k]*B[n][k]. 128x128 tile, BK=64 — kept for
// the output projection (2048x2048 split-K keeps grid fill there).
// ---------------------------------------------------------------------------
__global__ __launch_bounds__(256) void gemm_bt(
    const u16* __restrict__ A, const u16* __restrict__ B, void* __restrict__ Cv,
    int M, int N, int K, int lda, int ldb, int ldc,
    long batchA, long batchB, long batchC, int outBF16) {
  const int m0 = blockIdx.y << 7;
  const int n0 = blockIdx.x << 7;

  A += (long)blockIdx.z * batchA;
  B += (long)blockIdx.z * batchB;
  const long cbase = (long)blockIdx.z * batchC;

  __shared__ __align__(16) u16 As[128][64];
  __shared__ __align__(16) u16 Bs[128][64];

  const int t = threadIdx.x;
  const int lane = t & 63;
  const int wave = t >> 6;
  const int wm = (wave >> 1) << 6;
  const int wn = (wave & 1) << 6;
  const int quad = lane >> 4;
  const int mrow = lane & 15;
  const int sw8 = mrow & 7;

  floatx4 acc[4][4] = {};

  const int srow = lane >> 3;                       // 0..7 within issue
  const int gseg = (((lane & 7) ^ srow) << 3);      // u16 offset
  const u16* gA = A + (long)(m0 + (wave << 5) + srow) * lda + gseg;
  const u16* gB = B + (long)(n0 + (wave << 5) + srow) * ldb + gseg;

  for (int k0 = 0; k0 < K; k0 += 64) {
    __syncthreads();
#pragma unroll
    for (int ii = 0; ii < 4; ii++) {
      GLOAD_LDS16(gA + k0 + (size_t)(ii << 3) * lda, &As[(wave << 5) + (ii << 3)][0]);
      GLOAD_LDS16(gB + k0 + (size_t)(ii << 3) * ldb, &Bs[(wave << 5) + (ii << 3)][0]);
    }
    __syncthreads();

#pragma unroll
    for (int kh = 0; kh < 2; kh++) {
      const int sidx = ((kh << 2) | quad) ^ sw8;
      short8 af[4], bfr[4];
#pragma unroll
      for (int i = 0; i < 4; i++)
        af[i] = *(const short8*)&As[wm + (i << 4) + mrow][sidx << 3];
#pragma unroll
      for (int j = 0; j < 4; j++)
        bfr[j] = *(const short8*)&Bs[wn + (j << 4) + mrow][sidx << 3];
#pragma unroll
      for (int i = 0; i < 4; i++)
#pragma unroll
        for (int j = 0; j < 4; j++)
          acc[i][j] = __builtin_amdgcn_mfma_f32_16x16x32_bf16(af[i], bfr[j], acc[i][j], 0, 0, 0);
    }
  }

#pragma unroll
  for (int i = 0; i < 4; i++) {
    int row0 = m0 + wm + (i << 4) + (quad << 2);
#pragma unroll
    for (int j = 0; j < 4; j++) {
      int col = n0 + wn + (j << 4) + mrow;
#pragma unroll
      for (int r = 0; r < 4; r++) {
        long idx = cbase + (long)(row0 + r) * ldc + col;
        float val = acc[i][j][r];
        if (outBF16) ((u16*)Cv)[idx] = f2bf(val);
        else         ((float*)Cv)[idx] = val;
      }
    }
  }
}

// ---------------------------------------------------------------------------
// Transpose V (cols 4096..6143 of QKV, ld 6144) -> VT[d][s] (ld 2048).
// ---------------------------------------------------------------------------
__global__ __launch_bounds__(256) void transpose_v(const u16* __restrict__ src,
                                                   u16* __restrict__ dst) {
  __shared__ u16 tile[64][68];
  const int d0 = blockIdx.x << 6;
  const int s0 = blockIdx.y << 6;
  const int tx = (threadIdx.x & 15) << 2;
  const int ty = threadIdx.x >> 4;
#pragma unroll
  for (int rr = 0; rr < 64; rr += 16) {
    ushortx4 v = *(const ushortx4*)(src + (size_t)(s0 + ty + rr) * 6144 + d0 + tx);
    *(ushortx4*)&tile[ty + rr][tx] = v;
  }
  __syncthreads();
#pragma unroll
  for (int rr = 0; rr < 64; rr += 16) {
    int r = ty + rr;
    ushortx4 o;
    o.x = tile[tx + 0][r]; o.y = tile[tx + 1][r];
    o.z = tile[tx + 2][r]; o.w = tile[tx + 3][r];
    *(ushortx4*)(dst + (size_t)(d0 + r) * 2048 + s0 + tx) = o;
  }
}

// ---------------------------------------------------------------------------
// RoPE in-place on QKV (row stride 6144).
// q pre-scaled by log2(e)/sqrt(DH) so flash's softmax is a single exp2.
// ---------------------------------------------------------------------------
__global__ __launch_bounds__(256) void rope_qk(u16* __restrict__ qkv,
                                               const float* __restrict__ cs,
                                               const float* __restrict__ sn) {
  int idx = blockIdx.x * 256 + threadIdx.x;
  int p = idx & 63;
  int h = (idx >> 6) & 15;
  int s = idx >> 10;
  float c  = cs[(s << 6) | p];
  float si = sn[(s << 6) | p];
  float scale = blockIdx.y ? 1.0f : 0.12751743f;   // log2(e)/sqrt(128)
  size_t off = (size_t)s * 6144 + (blockIdx.y ? 2048 : 0) + (h << 7) + (p << 1);
  ushortx2 eo = *(ushortx2*)(qkv + off);
  float e = bf2f(eo.x), o = bf2f(eo.y);
  ushortx2 r;
  r.x = f2bf((e * c - o * si) * scale);
  r.y = f2bf((e * si + o * c) * scale);
  *(ushortx2*)(qkv + off) = r;
}

// ---------------------------------------------------------------------------
// Flash attention v4 (unchanged this round).
// ---------------------------------------------------------------------------
__global__ __launch_bounds__(256, 2) void flash_attn(
    const u16* __restrict__ QKVp, const u16* __restrict__ VTp,
    u16* __restrict__ ATp) {
  const int r0id = (int)blockIdx.x + ((int)blockIdx.y << 5);
  const int h    = r0id & 15;
  const int qsub = 31 - (r0id >> 4);
  const int q0 = qsub << 6;
  const int ktmax = qsub >> 1;

  __shared__ __align__(16) u16 Ks[128][128];    // K tile [s][d]   (32 KB)
  __shared__ __align__(16) u16 Vs[128][128];    // VT tile [d][s]  (32 KB)
  __shared__ __align__(16) u16 Ps[64][128];     // P tile  [q][s]  (16 KB)

  const int t = threadIdx.x;
  const int lane = t & 63;
  const int wave = t >> 6;
  const int quad = lane >> 4;
  const int mrow = lane & 15;
  const int sw   = mrow & 7;
  const int wmS = (wave & 1) << 5;
  const int wnS = (wave >> 1) << 6;
  const int wmV = (wave >> 1) << 6;
  const int wnP = (wave & 1) << 5;

  const int r4  = lane >> 4;
  const int seg = lane & 15;
  const int c0 = ((seg ^ r4) << 3);
  const int c4 = ((seg ^ (r4 + 4)) << 3);

  const u16* qbase = QKVp + (size_t)q0 * 6144 + (h << 7);
  const u16* kbase = QKVp + 2048 + (h << 7);
  const u16* vbase = VTp + (size_t)(h << 7) * 2048;

  short8 aq[2][4];
#pragma unroll
  for (int i = 0; i < 2; i++)
#pragma unroll
    for (int kk = 0; kk < 4; kk++)
      aq[i][kk] = *(const short8*)(qbase + (size_t)(wmS + (i << 4) + mrow) * 6144 +
                                   (kk << 5) + (quad << 3));

  const short8 ones = {0x3F80, 0x3F80, 0x3F80, 0x3F80,
                       0x3F80, 0x3F80, 0x3F80, 0x3F80};   // bf16 1.0 x8

  floatx4 Oa[4][2] = {};
  floatx4 Oa1[2] = {};

  const float C2 = 23.083120654223414f;         // 16*log2(e)

  for (int kt = 0; kt <= ktmax; kt++) {
    __syncthreads();                            // B1: prev PV reads done
    {
      int rr0 = wave << 5;
#pragma unroll
      for (int ii = 0; ii < 8; ii++) {
        int rr = rr0 + (ii << 2);
        GLOAD_LDS16(kbase + (size_t)((kt << 7) + rr + r4) * 6144 + ((ii & 1) ? c4 : c0),
                    &Ks[rr][0]);
        GLOAD_LDS16(vbase + (size_t)(rr + r4) * 2048 + (kt << 7) + ((ii & 1) ? c4 : c0),
                    &Vs[rr][0]);
      }
    }
    __syncthreads();                            // B2: staging complete

    floatx4 sa[2][4] = {};
#pragma unroll
    for (int kk = 0; kk < 4; kk++) {
      short8 bk[4];
#pragma unroll
      for (int j = 0; j < 4; j++)
        bk[j] = *(const short8*)&Ks[wnS + (j << 4) + mrow][(((kk << 2) | quad) ^ sw) << 3];
#pragma unroll
      for (int i = 0; i < 2; i++)
#pragma unroll
        for (int j = 0; j < 4; j++)
          sa[i][j] = __builtin_amdgcn_mfma_f32_16x16x32_bf16(aq[i][kk], bk[j], sa[i][j], 0, 0, 0);
    }
    if (kt == ktmax) {
#pragma unroll
      for (int i = 0; i < 2; i++)
#pragma unroll
        for (int j = 0; j < 4; j++)
#pragma unroll
          for (int r = 0; r < 4; r++) {
            int ql = q0 + wmS + (i << 4) + (quad << 2) + r;
            int sl = (kt << 7) + wnS + (j << 4) + mrow;
            if (sl > ql) sa[i][j][r] = -1e30f;
          }
    }
#pragma unroll
    for (int i = 0; i < 2; i++)
#pragma unroll
      for (int j = 0; j < 4; j++)
#pragma unroll
        for (int r = 0; r < 4; r++) {
          int row = wmS + (i << 4) + (quad << 2) + r;
          int col = wnS + (j << 4) + mrow;
          Ps[row][((((col >> 3) ^ (row & 7)) << 3) | (col & 7))] =
              f2bf(EXP2F(sa[i][j][r] - C2));
        }
    __syncthreads();                            // B3: P visible

#pragma unroll
    for (int kk = 0; kk < 4; kk++) {
      short8 av[4], bp[2];
#pragma unroll
      for (int i = 0; i < 4; i++)
        av[i] = *(const short8*)&Vs[wmV + (i << 4) + mrow][(((kk << 2) | quad) ^ sw) << 3];
#pragma unroll
      for (int j = 0; j < 2; j++)
        bp[j] = *(const short8*)&Ps[wnP + (j << 4) + mrow][(((kk << 2) | quad) ^ sw) << 3];
#pragma unroll
      for (int i = 0; i < 4; i++)
#pragma unroll
        for (int j = 0; j < 2; j++)
          Oa[i][j] = __builtin_amdgcn_mfma_f32_16x16x32_bf16(av[i], bp[j], Oa[i][j], 0, 0, 0);
#pragma unroll
      for (int j = 0; j < 2; j++)
        Oa1[j] = __builtin_amdgcn_mfma_f32_16x16x32_bf16(ones, bp[j], Oa1[j], 0, 0, 0);
    }
  }

  float linv[2];
#pragma unroll
  for (int j = 0; j < 2; j++) linv[j] = 1.f / Oa1[j][0];
#pragma unroll
  for (int i = 0; i < 4; i++) {
    int drow = (h << 7) + wmV + (i << 4) + (quad << 2);
#pragma unroll
    for (int j = 0; j < 2; j++) {
      int col = q0 + wnP + (j << 4) + mrow;
#pragma unroll
      for (int r = 0; r < 4; r++)
        ATp[(size_t)(drow + r) * 2048 + col] = f2bf(Oa[i][j][r] * linv[j]);
    }
  }
}

// out[i] = a[i] + b[i]  (split-K reduce, fp32x4)
__global__ __launch_bounds__(256) void reduce2(const floatx4* __restrict__ a,
                                               const floatx4* __restrict__ b,
                                               floatx4* __restrict__ o) {
  int i = blockIdx.x * 256 + threadIdx.x;
  o[i] = a[i] + b[i];
}

// ---------------------------------------------------------------------------
// Orchestration:
//   QKV = BT256x192(x, [wq;wk;wv]); VT = transpose(V); rope(Q,K);
//   AT  = flash_attn (512 blocks, heavy-first);  out = BT(AT, wo) (split-K=2).
// ---------------------------------------------------------------------------
extern "C" void kernel_launch(void* const* d_in, const int* in_sizes, int n_in,
                              void* d_out, int out_size, void* d_ws, size_t ws_size,
                              hipStream_t stream) {
  const float* x  = (const float*)d_in[0];
  const float* fc = (const float*)d_in[1];
  const float* fs = (const float*)d_in[2];
  const float* wq = (const float*)d_in[4];
  const float* wk = (const float*)d_in[5];
  const float* wv = (const float*)d_in[6];
  const float* wo = (const float*)d_in[7];
  float* out = (float*)d_out;

  char* ws = (char*)d_ws;
  const size_t MB = 1024 * 1024;
  u16*   XB   = (u16*)(ws + 0 * MB);
  u16*   WQKV = (u16*)(ws + 8 * MB);     // [wq;wk;wv] 6144x2048
  u16*   WOb  = (u16*)(ws + 32 * MB);
  u16*   QKV  = (u16*)(ws + 40 * MB);    // [s][6144]
  u16*   VT   = (u16*)(ws + 64 * MB);    // [d][s]
  u16*   AT   = (u16*)(ws + 72 * MB);    // [(h*128+d)][q]
  float* PART = (float*)(ws + 80 * MB);  // split-K partials (2 x 16 MB)

  int use_split = (ws_size >= 113 * MB);

  dim3 blk(256);
  cvt_all<<<dim3(4096, 5), blk, 0, stream>>>(
      (const floatx4*)x, (const floatx4*)wq, (const floatx4*)wk,
      (const floatx4*)wv, (const floatx4*)wo,
      (ushortx4*)XB, (ushortx4*)WQKV, (ushortx4*)WOb);

  // fused QKV projection: M=2048, N=6144, K=2048 — 256x192 tiles,
  // 8 x 32 = 256 blocks (exactly 1/CU), 512 threads.
  gemm256_bt<<<dim3(256), dim3(512), 0, stream>>>(XB, WQKV, QKV,
                                                  6144, 2048, 2048, 2048, 6144);

  transpose_v<<<dim3(32, 32), blk, 0, stream>>>(QKV + 4096, VT);
  rope_qk<<<dim3(8192, 2), blk, 0, stream>>>(QKV, fc, fs);

  flash_attn<<<dim3(32, 16), blk, 0, stream>>>(QKV, VT, AT);

  // final projection: out[r][j] = sum_q AT[r][q] * wo[j][q]
  if (use_split) {
    gemm_bt<<<dim3(16, 16, 2), blk, 0, stream>>>(AT, WOb, PART, 2048, 2048, 1024,
                                                 2048, 2048, 2048,
                                                 1024, 1024, (long)2048 * 2048, 0);
    reduce2<<<4096, blk, 0, stream>>>((const floatx4*)PART,
                                      (const floatx4*)(PART + (size_t)2048 * 2048),
                                      (floatx4*)out);
  } else {
    gemm_bt<<<dim3(16, 16, 1), blk, 0, stream>>>(AT, WOb, out, 2048, 2048, 2048,
                                                 2048, 2048, 2048, 0, 0, 0, 0);
  }
}